// Round 19
// baseline (366.251 us; speedup 1.0000x reference)
//
#include <hip/hip_runtime.h>

#define KDIM 128
#define NNODE 50000
#define CHSTRIDE 800000   // floats per chunk slab: 50000 nodes * 16 feats

typedef _Float16 f16x8 __attribute__((ext_vector_type(8)));
typedef _Float16 f16x4 __attribute__((ext_vector_type(4)));
typedef float f32x16 __attribute__((ext_vector_type(16)));

// ---------------------------------------------------------------------------
// CSR build. hist/scatter are XCD-chunked: block = (chunk<<3)|r, node-range r
// on (round-robin-dispatched) XCD r -> cnt/cursor atomics and col writes stay
// XCD-L2-local.
// ---------------------------------------------------------------------------
#define NRANGE 6250   // 50000 / 8
#define ECHUNK 3200   // edges per chunk; chunks = ceil(E/3200) = 250

__global__ void hist_kernel(const int* __restrict__ src, int* __restrict__ cnt, int E) {
    const int r = blockIdx.x & 7;
    const int chunk = blockIdx.x >> 3;
    const int lo = r * NRANGE, hi = lo + NRANGE;
    const int base = chunk * ECHUNK;
    const int end = min(base + ECHUNK, E);
    for (int i = base + threadIdx.x; i < end; i += 256) {
        int s = src[i];
        if (s >= lo && s < hi) atomicAdd(&cnt[s], 1);
    }
}

__global__ void scatter_kernel(const int* __restrict__ src, const int* __restrict__ dst,
                               int* cursor, int* __restrict__ col, int E) {
    const int r = blockIdx.x & 7;
    const int chunk = blockIdx.x >> 3;
    const int lo = r * NRANGE, hi = lo + NRANGE;
    const int base = chunk * ECHUNK;
    const int end = min(base + ECHUNK, E);
    for (int i = base + threadIdx.x; i < end; i += 256) {
        int s = src[i];
        if (s >= lo && s < hi) {
            int p = atomicAdd(&cursor[s], 1);
            col[p] = dst[i];
        }
    }
}

// Hierarchical exclusive scan of cnt[0..N) -> row_ptr, cursor (3 kernels).
__global__ void scan1_kernel(const int* __restrict__ cnt, int* __restrict__ row_ptr,
                             int* __restrict__ bsum, int N) {
    __shared__ int ws[4];
    const int t = threadIdx.x;
    const int lane = t & 63, w = t >> 6;
    const int i = blockIdx.x * 256 + t;
    int v = (i < N) ? cnt[i] : 0;
    int x = v;
    #pragma unroll
    for (int off = 1; off < 64; off <<= 1) {
        int u = __shfl_up(x, off);
        if (lane >= off) x += u;
    }
    if (lane == 63) ws[w] = x;
    __syncthreads();
    int wexcl = 0;
    #pragma unroll
    for (int k = 0; k < 4; k++) wexcl += (k < w) ? ws[k] : 0;
    if (i < N) row_ptr[i] = wexcl + x - v;      // block-local exclusive
    if (t == 255) bsum[blockIdx.x] = wexcl + x; // block total
}

__global__ void scan2_kernel(int* __restrict__ bsum, int NB) {
    __shared__ int ws[4];
    const int t = threadIdx.x;
    const int lane = t & 63, w = t >> 6;
    int v = (t < NB) ? bsum[t] : 0;
    int x = v;
    #pragma unroll
    for (int off = 1; off < 64; off <<= 1) {
        int u = __shfl_up(x, off);
        if (lane >= off) x += u;
    }
    if (lane == 63) ws[w] = x;
    __syncthreads();
    int wexcl = 0;
    #pragma unroll
    for (int k = 0; k < 4; k++) wexcl += (k < w) ? ws[k] : 0;
    if (t < NB) bsum[t] = wexcl + x - v;        // exclusive block offsets
}

__global__ void scan3_kernel(const int* __restrict__ bsum, int* __restrict__ row_ptr,
                             int* __restrict__ cursor, int N, int E) {
    const int i = blockIdx.x * 256 + threadIdx.x;
    if (i < N) {
        int v = row_ptr[i] + bsum[blockIdx.x];
        row_ptr[i] = v;
        cursor[i] = v;
    }
    if (i == 0) row_ptr[N] = E;
}

// Sort each CSR row's col values ascending -> deterministic summation order.
__global__ void sortrows_kernel(const int* __restrict__ row_ptr, int* __restrict__ col, int M) {
    int wid = (blockIdx.x * blockDim.x + threadIdx.x) >> 6;
    int lane = threadIdx.x & 63;
    if (wid >= M) return;
    int s = row_ptr[wid], e = row_ptr[wid + 1], len = e - s;
    if (len <= 1) return;
    if (len <= 64) {
        int v = (lane < len) ? col[s + lane] : 0x7fffffff;
        #pragma unroll
        for (int k = 2; k <= 64; k <<= 1) {
            #pragma unroll
            for (int j = k >> 1; j > 0; j >>= 1) {
                int o = __shfl_xor(v, j);
                bool dir = ((lane & k) == 0);
                bool smaller = ((lane & j) == 0);
                int mn = min(v, o), mx = max(v, o);
                v = (dir == smaller) ? mn : mx;
            }
        }
        if (lane < len) col[s + lane] = v;
    } else if (lane == 0) {
        for (int a = s + 1; a < e; a++) {
            int key = col[a];
            int b = a - 1;
            while (b >= s && col[b] > key) { col[b + 1] = col[b]; b--; }
            col[b + 1] = key;
        }
    }
}

// ---------------------------------------------------------------------------
// MaxK row-select (ballot radix, jax.lax.top_k ties: lower index wins).
// Input: lane holds elements (2*lane, 2*lane+1) of a 128-row. Output: masked.
// ---------------------------------------------------------------------------
__device__ __forceinline__ float2 maxk_row(float2 v, int lane) {
    unsigned int u0 = __float_as_uint(v.x);
    u0 = (u0 & 0x80000000u) ? ~u0 : (u0 | 0x80000000u);
    unsigned int u1 = __float_as_uint(v.y);
    u1 = (u1 & 0x80000000u) ? ~u1 : (u1 | 0x80000000u);

    unsigned int prefix = 0;
    int remaining = 32;
    #pragma unroll
    for (int b = 31; b >= 0; --b) {
        unsigned int candHi = (prefix >> b) | 1u;
        unsigned long long m0 = __ballot((u0 >> b) == candHi);
        unsigned long long m1 = __ballot((u1 >> b) == candHi);
        int cnt = __popcll(m0) + __popcll(m1);
        if (cnt >= remaining) prefix |= (1u << b);
        else remaining -= cnt;
    }

    unsigned long long e0 = __ballot(u0 == prefix);
    unsigned long long e1 = __ballot(u1 == prefix);
    unsigned long long g0 = __ballot(u0 > prefix);
    unsigned long long g1 = __ballot(u1 > prefix);
    int quota = 32 - (__popcll(g0) + __popcll(g1));
    unsigned long long below = (1ULL << lane) - 1ULL;
    int rank0 = __popcll(e0 & below) + __popcll(e1 & below);
    int rank1 = rank0 + (int)((e0 >> lane) & 1ULL);
    bool k0 = (u0 > prefix) || (((e0 >> lane) & 1ULL) && rank0 < quota);
    bool k1 = (u1 > prefix) || (((e1 >> lane) & 1ULL) && rank1 < quota);

    float2 o;
    o.x = k0 ? v.x : 0.0f;
    o.y = k1 ? v.y : 0.0f;
    return o;
}

// ---------------------------------------------------------------------------
// Aggregation (feature-chunked, 4 nodes/wave): chunk c = blockIdx&7 -> one
// chunk per XCD so gathers hit the 3.2MB L2-resident slab. Block = 16 nodes;
// contiguous col range staged into LDS. MSHR-floor ~55-58us (6.4M 64B lines
// at ~32 outstanding misses x ~200cy L2 latency per CU) — probed from five
// directions (R8/R9/R12/R16/R17); gather-form at this floor is the winner.
// ---------------------------------------------------------------------------
#define ANPB 16    // nodes per block
#define AECAP 1024 // LDS edge cap (block edges ~N(256,16^2); exact fallback)

__global__ __launch_bounds__(256)
void aggregate_kernel(const float* __restrict__ hsc, const int* __restrict__ row_ptr,
                      const int* __restrict__ col, float* __restrict__ agg, int M) {
    __shared__ int cols[AECAP];
    const int c = blockIdx.x & 7;
    const int g = blockIdx.x >> 3;
    const int n0 = g * ANPB;
    const int tid = threadIdx.x;
    const int w = tid >> 6;
    const int lane = tid & 63;
    const int ng = lane >> 4;        // node within wave: 0..3
    const int e2 = (lane >> 3) & 1;  // edge slot
    const int f2 = lane & 7;         // feature pair

    const int nend = min(n0 + ANPB, M);
    const int base0 = row_ptr[n0];
    const int ecount = row_ptr[nend] - base0;
    const bool fits = (ecount <= AECAP);
    if (fits) {
        for (int i = tid; i < ecount; i += 256) cols[i] = col[base0 + i];
    }
    __syncthreads();

    const int n = n0 + w * 4 + ng;
    const bool valid = (n < M);
    const int s = valid ? (row_ptr[n] - base0) : 0;
    const int e = valid ? (row_ptr[n + 1] - base0) : 0;
    const char* bp = (const char*)(hsc + (size_t)c * CHSTRIDE) + f2 * 8;

    float ax = 0.f, ay = 0.f, bx = 0.f, by = 0.f;
    int j = s + e2;
    if (fits) {
        for (; j + 2 < e; j += 4) {
            unsigned o0 = (unsigned)cols[j] << 6;
            unsigned o1 = (unsigned)cols[j + 2] << 6;
            float2 v0 = *(const float2*)(bp + o0);
            float2 v1 = *(const float2*)(bp + o1);
            ax += v0.x; ay += v0.y;
            bx += v1.x; by += v1.y;
        }
        if (j < e) {
            float2 v = *(const float2*)(bp + ((unsigned)cols[j] << 6));
            ax += v.x; ay += v.y;
        }
    } else {
        const int* cg = col + base0;
        for (; j + 2 < e; j += 4) {
            unsigned o0 = (unsigned)cg[j] << 6;
            unsigned o1 = (unsigned)cg[j + 2] << 6;
            float2 v0 = *(const float2*)(bp + o0);
            float2 v1 = *(const float2*)(bp + o1);
            ax += v0.x; ay += v0.y;
            bx += v1.x; by += v1.y;
        }
        if (j < e) {
            float2 v = *(const float2*)(bp + ((unsigned)cg[j] << 6));
            ax += v.x; ay += v.y;
        }
    }

    float tx = ax + bx, ty = ay + by;
    tx += __shfl_xor(tx, 8);
    ty += __shfl_xor(ty, 8);
    if (valid && e2 == 0) {
        float inv = 1.0f / ((float)(e - s) + 1e-6f);
        float2 o;
        o.x = tx * inv;
        o.y = ty * inv;
        ((float2*)(agg + (size_t)n * KDIM + c * 16))[f2] = o;
    }
}

// ---------------------------------------------------------------------------
// Weight prep: transpose to [n][k] and split f32 -> fp16 (hi, lo).
// ---------------------------------------------------------------------------
__global__ void conv_wt_kernel(const float* __restrict__ W_in,
                               const float* __restrict__ W_self,
                               const float* __restrict__ W_neigh,
                               const float* __restrict__ W_out,
                               _Float16* __restrict__ wb) {
    int t = blockIdx.x * blockDim.x + threadIdx.x;
    if (t < 81920) {
        int m = t >> 14;            // 0..4
        int e = t & 16383;
        int n = e >> 7, k = e & 127;
        const float* S = (m == 0) ? W_in
                       : (m <= 2) ? (W_self + (size_t)(m - 1) * 16384)
                                  : (W_neigh + (size_t)(m - 3) * 16384);
        float v = S[k * 128 + n];
        _Float16 hi = (_Float16)v;
        _Float16 lo = (_Float16)(v - (float)hi);
        int pair = m * 2;
        wb[(size_t)pair * 16384 + n * 128 + k] = hi;
        wb[(size_t)(pair + 1) * 16384 + n * 128 + k] = lo;
    } else if (t < 90112) {
        int e = t - 81920;          // [0, 8192)
        int n = e >> 7, k = e & 127;
        float v = W_out[k * 64 + n];
        _Float16 hi = (_Float16)v;
        _Float16 lo = (_Float16)(v - (float)hi);
        wb[(size_t)10 * 16384 + e] = hi;
        wb[(size_t)11 * 16384 + e] = lo;
    }
}

// ---------------------------------------------------------------------------
// Split-fp16 MFMA GEMM: C[M,BN] = A1 @ B1 (+ A2 @ B2) (+ bias), K=128, f32 I/O.
// a@b = hi@hi + hi@lo + lo@hi (lo@lo dropped, ~2^-22 rel).
// __launch_bounds__(256, 1): R19 fix — the bare (256) annotation made hipcc
// target 8 waves/SIMD and cap the allocator at ~64 VGPRs (observed 40-72 all
// session), serializing the prologue A-loads and B-preloads into latency
// chains (MfmaUtil 5.7%, every pipe idle). min-waves=1 lifts the cap so the
// batched loads actually stay in flight; ~6 blocks/CU of parallelism remains.
// FUSE_MAXK: h-tile -> LDS overlay, ballot-radix top-32, chunked hsc write.
// ---------------------------------------------------------------------------
template <int BN, bool DUAL, bool BIAS, bool A1CHUNK, bool FUSE_MAXK>
__global__ __launch_bounds__(256, 1)
void gemm_mfma(const float* __restrict__ A1, const float* __restrict__ A2,
               const _Float16* __restrict__ B1h, const _Float16* __restrict__ B1l,
               const _Float16* __restrict__ B2h, const _Float16* __restrict__ B2l,
               const float* __restrict__ bias, float* __restrict__ C,
               float* __restrict__ hsc_out, int M) {
    constexpr int BM = (BN == 128) ? 32 : 64;
    constexpr int NSRC = DUAL ? 2 : 1;
    constexpr int AREG = BM / 8;        // float4 per thread per source: 4 or 8
    constexpr int LOOFF = BM * 256;     // lo-plane LDS offset

    __shared__ __align__(16) char Alds[2 * BM * 256];  // 16KB (BM=32) / 32KB

    const int tid = threadIdx.x;
    const int w = tid >> 6;
    const int lane = tid & 63;
    const int l31 = lane & 31;
    const int kslot = lane >> 5;
    const int row0 = blockIdx.x * BM;

    const int n0 = (BN == 128) ? w * 32 : (w & 1) * 32;
    const int mt0 = (BN == 128) ? 0 : (w >> 1);

    // staging indices: thread covers rows (tid>>5)+8p, float4-col k4=tid&31
    const int srow = tid >> 5;
    const int k4 = tid & 31;

    f32x16 acc;
    #pragma unroll
    for (int e = 0; e < 16; e++) acc[e] = 0.0f;

    float4 pa[AREG];
    // ---- prologue: load source 0 into regs ----
    #pragma unroll
    for (int p = 0; p < AREG; p++) {
        int row = srow + p * 8;
        float4 v = make_float4(0.f, 0.f, 0.f, 0.f);
        if (row0 + row < M) {
            if (A1CHUNK)
                v = *(const float4*)(A1 + (size_t)(k4 >> 2) * CHSTRIDE
                                        + (size_t)(row0 + row) * 16 + (k4 & 3) * 4);
            else
                v = *(const float4*)(A1 + (size_t)(row0 + row) * KDIM + k4 * 4);
        }
        pa[p] = v;
    }

    #pragma unroll
    for (int s = 0; s < NSRC; s++) {
        if (s) __syncthreads();   // previous source's MFMA reads done
        // ---- B-fragment preload: ALL 16 loads issued before any MFMA ----
        const _Float16* Bh = s ? B2h : B1h;
        const _Float16* Bl = s ? B2l : B1l;
        const _Float16* bph = Bh + (size_t)(n0 + l31) * 128 + kslot * 8;
        const _Float16* bpl = Bl + (size_t)(n0 + l31) * 128 + kslot * 8;
        f16x8 bhr[8], blr[8];
        #pragma unroll
        for (int kb = 0; kb < 8; kb++) {
            bhr[kb] = *(const f16x8*)(bph + kb * 16);
            blr[kb] = *(const f16x8*)(bpl + kb * 16);
        }

        // ---- regs -> (hi,lo) fp16 swizzled LDS ----
        #pragma unroll
        for (int p = 0; p < AREG; p++) {
            int row = srow + p * 8;
            float4 v = pa[p];
            _Float16 h0 = (_Float16)v.x, h1 = (_Float16)v.y,
                     h2 = (_Float16)v.z, h3 = (_Float16)v.w;
            f16x4 hv = {h0, h1, h2, h3};
            f16x4 lv = {(_Float16)(v.x - (float)h0), (_Float16)(v.y - (float)h1),
                        (_Float16)(v.z - (float)h2), (_Float16)(v.w - (float)h3)};
            int boff = (k4 * 8) ^ ((row & 7) << 4);
            *(f16x4*)(Alds + row * 256 + boff) = hv;
            *(f16x4*)(Alds + LOOFF + row * 256 + boff) = lv;
        }
        __syncthreads();

        // ---- prefetch source s+1 (A2 = plain layout) while MFMA below ----
        if (s + 1 < NSRC) {
            #pragma unroll
            for (int p = 0; p < AREG; p++) {
                int row = srow + p * 8;
                float4 v = make_float4(0.f, 0.f, 0.f, 0.f);
                if (row0 + row < M)
                    v = *(const float4*)(A2 + (size_t)(row0 + row) * KDIM + k4 * 4);
                pa[p] = v;
            }
        }

        // ---- K-loop: pure LDS reads + register B ----
        const int arow = mt0 * 32 + l31;
        #pragma unroll
        for (int kb = 0; kb < 8; kb++) {
            int boff = ((kb * 2 + kslot) * 16) ^ ((arow & 7) << 4);
            const char* rp = Alds + arow * 256 + boff;
            f16x8 ah = *(const f16x8*)(rp);
            f16x8 al = *(const f16x8*)(rp + LOOFF);
            acc = __builtin_amdgcn_mfma_f32_32x32x16_f16(al, bhr[kb], acc, 0, 0, 0);
            acc = __builtin_amdgcn_mfma_f32_32x32x16_f16(ah, blr[kb], acc, 0, 0, 0);
            acc = __builtin_amdgcn_mfma_f32_32x32x16_f16(ah, bhr[kb], acc, 0, 0, 0);
        }
    }

    float bv = 0.0f;
    if (BIAS) bv = bias[n0 + l31];

    if constexpr (FUSE_MAXK) {
        // ---- h-tile -> LDS (staging LDS dead; BM*512B = exact overlay) ----
        __syncthreads();
        float* ht = (float*)Alds;   // [BM][128]
        #pragma unroll
        for (int r = 0; r < 16; r++) {
            int row = (r & 3) + 8 * (r >> 2) + 4 * kslot;
            ht[row * 128 + n0 + l31] = acc[r] + bv;
        }
        __syncthreads();
        // ---- per-row top-32 + chunked hsc write; wave w: rows w*8.. ----
        float* slab = hsc_out + (size_t)(lane >> 3) * CHSTRIDE;
        #pragma unroll 1
        for (int rr = 0; rr < BM / 4; rr++) {
            int row = w * (BM / 4) + rr;
            float2 v = *(const float2*)(ht + row * 128 + lane * 2);
            float2 o = maxk_row(v, lane);
            int n = row0 + row;
            if (n < M)
                ((float2*)slab)[(size_t)n * 8 + (lane & 7)] = o;
        }
    } else {
        #pragma unroll
        for (int r = 0; r < 16; r++) {
            int row = row0 + mt0 * 32 + (r & 3) + 8 * (r >> 2) + 4 * kslot;
            if (row < M) C[(size_t)row * BN + n0 + l31] = acc[r] + bv;
        }
    }
}

// ---------------------------------------------------------------------------
extern "C" void kernel_launch(void* const* d_in, const int* in_sizes, int n_in,
                              void* d_out, int out_size, void* d_ws, size_t ws_size,
                              hipStream_t stream) {
    const float* x       = (const float*)d_in[0];
    const float* W_in    = (const float*)d_in[1];
    const float* b_in    = (const float*)d_in[2];
    const float* W_self  = (const float*)d_in[3];
    const float* W_neigh = (const float*)d_in[4];
    const float* W_out   = (const float*)d_in[5];
    const float* b_out   = (const float*)d_in[6];
    const int*   eidx    = (const int*)d_in[7];

    const int N = NNODE, E = 800000;
    const int* src = eidx;
    const int* dst = eidx + E;

    char* ws = (char*)d_ws;
    float* slabA = (float*)(ws);                // 25.6 MB: layer-1 hsc, later h
    float* slabB = (float*)(ws + 25600000);     // 25.6 MB: layer-2 hsc
    float* agg   = (float*)(ws + 51200000);     // 25.6 MB
    int* cnt     = (int*)(ws + 76800000);       // 200 KB
    int* row_ptr = (int*)(ws + 77000000);       // 200 KB
    int* cursor  = (int*)(ws + 77200016);       // 200 KB
    int* col     = (int*)(ws + 77400016);       // 3.2 MB
    _Float16* wb = (_Float16*)(ws + 80600016);  // 384 KB weight slots
    int* bsum    = (int*)(ws + 81000016);       // 1 KB scan block sums

    const _Float16* WinT_h  = wb + (size_t)0 * 16384;
    const _Float16* WinT_l  = wb + (size_t)1 * 16384;
    const _Float16* WoutT_h = wb + (size_t)10 * 16384;
    const _Float16* WoutT_l = wb + (size_t)11 * 16384;

    const int NB = (N + 255) / 256;                   // 196 scan blocks
    const int EG = ((E + ECHUNK - 1) / ECHUNK) * 8;   // 2000 xcd-chunked blocks
    const int AG = ((N + ANPB - 1) / ANPB) * 8;       // 25000 aggregate blocks
    const int G32 = (N + 31) / 32;                    // 1563 BM=32 gemm blocks
    const int G64 = (N + 63) / 64;                    // 782 BM=64 gemm blocks

    hipMemsetAsync(cnt, 0, N * sizeof(int), stream);
    hist_kernel<<<EG, 256, 0, stream>>>(src, cnt, E);
    scan1_kernel<<<NB, 256, 0, stream>>>(cnt, row_ptr, bsum, N);
    scan2_kernel<<<1, 256, 0, stream>>>(bsum, NB);
    scan3_kernel<<<NB, 256, 0, stream>>>(bsum, row_ptr, cursor, N, E);
    scatter_kernel<<<EG, 256, 0, stream>>>(src, dst, cursor, col, E);
    sortrows_kernel<<<(N + 3) / 4, 256, 0, stream>>>(row_ptr, col, N);
    conv_wt_kernel<<<(90112 + 255) / 256, 256, 0, stream>>>(W_in, W_self, W_neigh, W_out, wb);

    // layer-1 hs = maxk(x @ W_in + b_in)  [fused] -> slabA (chunked)
    gemm_mfma<128, false, true, false, true><<<G32, 256, 0, stream>>>(
        x, nullptr, WinT_h, WinT_l, nullptr, nullptr, b_in, nullptr, slabA, N);

    // layer 1: agg(slabA); hs2 = maxk(hs@Ws0 + agg@Wn0) [fused] -> slabB
    aggregate_kernel<<<AG, 256, 0, stream>>>(slabA, row_ptr, col, agg, N);
    gemm_mfma<128, true, false, true, true><<<G32, 256, 0, stream>>>(
        slabA, agg, wb + (size_t)2 * 16384, wb + (size_t)3 * 16384,
        wb + (size_t)6 * 16384, wb + (size_t)7 * 16384, nullptr, nullptr, slabB, N);

    // layer 2: agg(slabB); h = hs@Ws1 + agg@Wn1 (plain f32) -> slabA region
    aggregate_kernel<<<AG, 256, 0, stream>>>(slabB, row_ptr, col, agg, N);
    gemm_mfma<128, true, false, true, false><<<G32, 256, 0, stream>>>(
        slabB, agg, wb + (size_t)4 * 16384, wb + (size_t)5 * 16384,
        wb + (size_t)8 * 16384, wb + (size_t)9 * 16384, nullptr, slabA, nullptr, N);

    // out = h @ W_out + b_out
    gemm_mfma<64, false, true, false, false><<<G64, 256, 0, stream>>>(
        slabA, nullptr, WoutT_h, WoutT_l, nullptr, nullptr, b_out, (float*)d_out, nullptr, N);
}

// Round 20
// 355.176 us; speedup vs baseline: 1.0312x; 1.0312x over previous
//
#include <hip/hip_runtime.h>

#define KDIM 128
#define NNODE 50000
#define CHSTRIDE 800000   // floats per chunk slab: 50000 nodes * 16 feats

typedef _Float16 f16x8 __attribute__((ext_vector_type(8)));
typedef _Float16 f16x4 __attribute__((ext_vector_type(4)));
typedef float f32x16 __attribute__((ext_vector_type(16)));

// ---------------------------------------------------------------------------
// CSR build. hist/scatter are XCD-chunked: block = (chunk<<3)|r, node-range r
// on (round-robin-dispatched) XCD r -> cnt/cursor atomics and col writes stay
// XCD-L2-local.
// ---------------------------------------------------------------------------
#define NRANGE 6250   // 50000 / 8
#define ECHUNK 3200   // edges per chunk; chunks = ceil(E/3200) = 250

__global__ void hist_kernel(const int* __restrict__ src, int* __restrict__ cnt, int E) {
    const int r = blockIdx.x & 7;
    const int chunk = blockIdx.x >> 3;
    const int lo = r * NRANGE, hi = lo + NRANGE;
    const int base = chunk * ECHUNK;
    const int end = min(base + ECHUNK, E);
    for (int i = base + threadIdx.x; i < end; i += 256) {
        int s = src[i];
        if (s >= lo && s < hi) atomicAdd(&cnt[s], 1);
    }
}

__global__ void scatter_kernel(const int* __restrict__ src, const int* __restrict__ dst,
                               int* cursor, int* __restrict__ col, int E) {
    const int r = blockIdx.x & 7;
    const int chunk = blockIdx.x >> 3;
    const int lo = r * NRANGE, hi = lo + NRANGE;
    const int base = chunk * ECHUNK;
    const int end = min(base + ECHUNK, E);
    for (int i = base + threadIdx.x; i < end; i += 256) {
        int s = src[i];
        if (s >= lo && s < hi) {
            int p = atomicAdd(&cursor[s], 1);
            col[p] = dst[i];
        }
    }
}

// Hierarchical exclusive scan of cnt[0..N) -> row_ptr, cursor (3 kernels).
__global__ void scan1_kernel(const int* __restrict__ cnt, int* __restrict__ row_ptr,
                             int* __restrict__ bsum, int N) {
    __shared__ int ws[4];
    const int t = threadIdx.x;
    const int lane = t & 63, w = t >> 6;
    const int i = blockIdx.x * 256 + t;
    int v = (i < N) ? cnt[i] : 0;
    int x = v;
    #pragma unroll
    for (int off = 1; off < 64; off <<= 1) {
        int u = __shfl_up(x, off);
        if (lane >= off) x += u;
    }
    if (lane == 63) ws[w] = x;
    __syncthreads();
    int wexcl = 0;
    #pragma unroll
    for (int k = 0; k < 4; k++) wexcl += (k < w) ? ws[k] : 0;
    if (i < N) row_ptr[i] = wexcl + x - v;      // block-local exclusive
    if (t == 255) bsum[blockIdx.x] = wexcl + x; // block total
}

__global__ void scan2_kernel(int* __restrict__ bsum, int NB) {
    __shared__ int ws[4];
    const int t = threadIdx.x;
    const int lane = t & 63, w = t >> 6;
    int v = (t < NB) ? bsum[t] : 0;
    int x = v;
    #pragma unroll
    for (int off = 1; off < 64; off <<= 1) {
        int u = __shfl_up(x, off);
        if (lane >= off) x += u;
    }
    if (lane == 63) ws[w] = x;
    __syncthreads();
    int wexcl = 0;
    #pragma unroll
    for (int k = 0; k < 4; k++) wexcl += (k < w) ? ws[k] : 0;
    if (t < NB) bsum[t] = wexcl + x - v;        // exclusive block offsets
}

__global__ void scan3_kernel(const int* __restrict__ bsum, int* __restrict__ row_ptr,
                             int* __restrict__ cursor, int N, int E) {
    const int i = blockIdx.x * 256 + threadIdx.x;
    if (i < N) {
        int v = row_ptr[i] + bsum[blockIdx.x];
        row_ptr[i] = v;
        cursor[i] = v;
    }
    if (i == 0) row_ptr[N] = E;
}

// Sort each CSR row's col values ascending -> deterministic summation order.
__global__ void sortrows_kernel(const int* __restrict__ row_ptr, int* __restrict__ col, int M) {
    int wid = (blockIdx.x * blockDim.x + threadIdx.x) >> 6;
    int lane = threadIdx.x & 63;
    if (wid >= M) return;
    int s = row_ptr[wid], e = row_ptr[wid + 1], len = e - s;
    if (len <= 1) return;
    if (len <= 64) {
        int v = (lane < len) ? col[s + lane] : 0x7fffffff;
        #pragma unroll
        for (int k = 2; k <= 64; k <<= 1) {
            #pragma unroll
            for (int j = k >> 1; j > 0; j >>= 1) {
                int o = __shfl_xor(v, j);
                bool dir = ((lane & k) == 0);
                bool smaller = ((lane & j) == 0);
                int mn = min(v, o), mx = max(v, o);
                v = (dir == smaller) ? mn : mx;
            }
        }
        if (lane < len) col[s + lane] = v;
    } else if (lane == 0) {
        for (int a = s + 1; a < e; a++) {
            int key = col[a];
            int b = a - 1;
            while (b >= s && col[b] > key) { col[b + 1] = col[b]; b--; }
            col[b + 1] = key;
        }
    }
}

// ---------------------------------------------------------------------------
// MaxK row-select (ballot radix, jax.lax.top_k ties: lower index wins).
// Input: lane holds elements (2*lane, 2*lane+1) of a 128-row. Output: masked.
// ---------------------------------------------------------------------------
__device__ __forceinline__ float2 maxk_row(float2 v, int lane) {
    unsigned int u0 = __float_as_uint(v.x);
    u0 = (u0 & 0x80000000u) ? ~u0 : (u0 | 0x80000000u);
    unsigned int u1 = __float_as_uint(v.y);
    u1 = (u1 & 0x80000000u) ? ~u1 : (u1 | 0x80000000u);

    unsigned int prefix = 0;
    int remaining = 32;
    #pragma unroll
    for (int b = 31; b >= 0; --b) {
        unsigned int candHi = (prefix >> b) | 1u;
        unsigned long long m0 = __ballot((u0 >> b) == candHi);
        unsigned long long m1 = __ballot((u1 >> b) == candHi);
        int cnt = __popcll(m0) + __popcll(m1);
        if (cnt >= remaining) prefix |= (1u << b);
        else remaining -= cnt;
    }

    unsigned long long e0 = __ballot(u0 == prefix);
    unsigned long long e1 = __ballot(u1 == prefix);
    unsigned long long g0 = __ballot(u0 > prefix);
    unsigned long long g1 = __ballot(u1 > prefix);
    int quota = 32 - (__popcll(g0) + __popcll(g1));
    unsigned long long below = (1ULL << lane) - 1ULL;
    int rank0 = __popcll(e0 & below) + __popcll(e1 & below);
    int rank1 = rank0 + (int)((e0 >> lane) & 1ULL);
    bool k0 = (u0 > prefix) || (((e0 >> lane) & 1ULL) && rank0 < quota);
    bool k1 = (u1 > prefix) || (((e1 >> lane) & 1ULL) && rank1 < quota);

    float2 o;
    o.x = k0 ? v.x : 0.0f;
    o.y = k1 ? v.y : 0.0f;
    return o;
}

// ---------------------------------------------------------------------------
// Aggregation (feature-chunked, 4 nodes/wave): chunk c = blockIdx&7 -> one
// chunk per XCD so gathers hit the 3.2MB L2-resident slab. Block = 16 nodes;
// contiguous col range staged into LDS. MSHR-floor ~55-58us (6.4M 64B lines
// at ~32 outstanding misses x ~200cy L2 latency per CU) — probed from five
// directions (R8/R9/R12/R16/R17); gather-form at this floor is the winner.
// ---------------------------------------------------------------------------
#define ANPB 16    // nodes per block
#define AECAP 1024 // LDS edge cap (block edges ~N(256,16^2); exact fallback)

__global__ __launch_bounds__(256)
void aggregate_kernel(const float* __restrict__ hsc, const int* __restrict__ row_ptr,
                      const int* __restrict__ col, float* __restrict__ agg, int M) {
    __shared__ int cols[AECAP];
    const int c = blockIdx.x & 7;
    const int g = blockIdx.x >> 3;
    const int n0 = g * ANPB;
    const int tid = threadIdx.x;
    const int w = tid >> 6;
    const int lane = tid & 63;
    const int ng = lane >> 4;        // node within wave: 0..3
    const int e2 = (lane >> 3) & 1;  // edge slot
    const int f2 = lane & 7;         // feature pair

    const int nend = min(n0 + ANPB, M);
    const int base0 = row_ptr[n0];
    const int ecount = row_ptr[nend] - base0;
    const bool fits = (ecount <= AECAP);
    if (fits) {
        for (int i = tid; i < ecount; i += 256) cols[i] = col[base0 + i];
    }
    __syncthreads();

    const int n = n0 + w * 4 + ng;
    const bool valid = (n < M);
    const int s = valid ? (row_ptr[n] - base0) : 0;
    const int e = valid ? (row_ptr[n + 1] - base0) : 0;
    const char* bp = (const char*)(hsc + (size_t)c * CHSTRIDE) + f2 * 8;

    float ax = 0.f, ay = 0.f, bx = 0.f, by = 0.f;
    int j = s + e2;
    if (fits) {
        for (; j + 2 < e; j += 4) {
            unsigned o0 = (unsigned)cols[j] << 6;
            unsigned o1 = (unsigned)cols[j + 2] << 6;
            float2 v0 = *(const float2*)(bp + o0);
            float2 v1 = *(const float2*)(bp + o1);
            ax += v0.x; ay += v0.y;
            bx += v1.x; by += v1.y;
        }
        if (j < e) {
            float2 v = *(const float2*)(bp + ((unsigned)cols[j] << 6));
            ax += v.x; ay += v.y;
        }
    } else {
        const int* cg = col + base0;
        for (; j + 2 < e; j += 4) {
            unsigned o0 = (unsigned)cg[j] << 6;
            unsigned o1 = (unsigned)cg[j + 2] << 6;
            float2 v0 = *(const float2*)(bp + o0);
            float2 v1 = *(const float2*)(bp + o1);
            ax += v0.x; ay += v0.y;
            bx += v1.x; by += v1.y;
        }
        if (j < e) {
            float2 v = *(const float2*)(bp + ((unsigned)cg[j] << 6));
            ax += v.x; ay += v.y;
        }
    }

    float tx = ax + bx, ty = ay + by;
    tx += __shfl_xor(tx, 8);
    ty += __shfl_xor(ty, 8);
    if (valid && e2 == 0) {
        float inv = 1.0f / ((float)(e - s) + 1e-6f);
        float2 o;
        o.x = tx * inv;
        o.y = ty * inv;
        ((float2*)(agg + (size_t)n * KDIM + c * 16))[f2] = o;
    }
}

// ---------------------------------------------------------------------------
// Weight prep: transpose to [n][k] and split f32 -> fp16 (hi, lo).
// ---------------------------------------------------------------------------
__global__ void conv_wt_kernel(const float* __restrict__ W_in,
                               const float* __restrict__ W_self,
                               const float* __restrict__ W_neigh,
                               const float* __restrict__ W_out,
                               _Float16* __restrict__ wb) {
    int t = blockIdx.x * blockDim.x + threadIdx.x;
    if (t < 81920) {
        int m = t >> 14;            // 0..4
        int e = t & 16383;
        int n = e >> 7, k = e & 127;
        const float* S = (m == 0) ? W_in
                       : (m <= 2) ? (W_self + (size_t)(m - 1) * 16384)
                                  : (W_neigh + (size_t)(m - 3) * 16384);
        float v = S[k * 128 + n];
        _Float16 hi = (_Float16)v;
        _Float16 lo = (_Float16)(v - (float)hi);
        int pair = m * 2;
        wb[(size_t)pair * 16384 + n * 128 + k] = hi;
        wb[(size_t)(pair + 1) * 16384 + n * 128 + k] = lo;
    } else if (t < 90112) {
        int e = t - 81920;          // [0, 8192)
        int n = e >> 7, k = e & 127;
        float v = W_out[k * 64 + n];
        _Float16 hi = (_Float16)v;
        _Float16 lo = (_Float16)(v - (float)hi);
        wb[(size_t)10 * 16384 + e] = hi;
        wb[(size_t)11 * 16384 + e] = lo;
    }
}

// ---------------------------------------------------------------------------
// Split-fp16 MFMA GEMM: C[M,BN] = A1 @ B1 (+ A2 @ B2) (+ bias), K=128, f32 I/O.
// a@b = hi@hi + hi@lo + lo@hi (lo@lo dropped, ~2^-22 rel).
// B-fragments fully preloaded (R15). FUSE_MAXK: ballot-radix top-32 epilogue
// writing chunked hsc. FUSE_OUT (R20): instead of writing h to global and
// re-reading it in a 4th GEMM, stage the 32x128 h-tile into the dead staging
// LDS (16B-unit XOR swizzle -> conflict-light both directions) and have
// waves 0-1 compute out = h @ W_outT + b_out directly to d_out. Arithmetic
// identical to the standalone out-GEMM (same f32 h, same hi/lo split, same
// MFMA order) -> bit-identical output; saves a dispatch + 51 MB traffic.
// ---------------------------------------------------------------------------
template <int BN, bool DUAL, bool BIAS, bool A1CHUNK, bool FUSE_MAXK, bool FUSE_OUT>
__global__ __launch_bounds__(256)
void gemm_mfma(const float* __restrict__ A1, const float* __restrict__ A2,
               const _Float16* __restrict__ B1h, const _Float16* __restrict__ B1l,
               const _Float16* __restrict__ B2h, const _Float16* __restrict__ B2l,
               const float* __restrict__ bias, float* __restrict__ C,
               float* __restrict__ hsc_out,
               const _Float16* __restrict__ Oh, const _Float16* __restrict__ Ol,
               const float* __restrict__ obias, float* __restrict__ oout, int M) {
    constexpr int BM = (BN == 128) ? 32 : 64;
    constexpr int NSRC = DUAL ? 2 : 1;
    constexpr int AREG = BM / 8;        // float4 per thread per source: 4 or 8
    constexpr int LOOFF = BM * 256;     // lo-plane LDS offset

    __shared__ __align__(16) char Alds[2 * BM * 256];  // 16KB (BM=32) / 32KB

    const int tid = threadIdx.x;
    const int w = tid >> 6;
    const int lane = tid & 63;
    const int l31 = lane & 31;
    const int kslot = lane >> 5;
    const int row0 = blockIdx.x * BM;

    const int n0 = (BN == 128) ? w * 32 : (w & 1) * 32;
    const int mt0 = (BN == 128) ? 0 : (w >> 1);

    // staging indices: thread covers rows (tid>>5)+8p, float4-col k4=tid&31
    const int srow = tid >> 5;
    const int k4 = tid & 31;

    f32x16 acc;
    #pragma unroll
    for (int e = 0; e < 16; e++) acc[e] = 0.0f;

    float4 pa[AREG];
    // ---- prologue: load source 0 into regs ----
    #pragma unroll
    for (int p = 0; p < AREG; p++) {
        int row = srow + p * 8;
        float4 v = make_float4(0.f, 0.f, 0.f, 0.f);
        if (row0 + row < M) {
            if (A1CHUNK)
                v = *(const float4*)(A1 + (size_t)(k4 >> 2) * CHSTRIDE
                                        + (size_t)(row0 + row) * 16 + (k4 & 3) * 4);
            else
                v = *(const float4*)(A1 + (size_t)(row0 + row) * KDIM + k4 * 4);
        }
        pa[p] = v;
    }

    #pragma unroll
    for (int s = 0; s < NSRC; s++) {
        if (s) __syncthreads();   // previous source's MFMA reads done
        // ---- B-fragment preload: ALL 16 loads issued before any MFMA ----
        const _Float16* Bh = s ? B2h : B1h;
        const _Float16* Bl = s ? B2l : B1l;
        const _Float16* bph = Bh + (size_t)(n0 + l31) * 128 + kslot * 8;
        const _Float16* bpl = Bl + (size_t)(n0 + l31) * 128 + kslot * 8;
        f16x8 bhr[8], blr[8];
        #pragma unroll
        for (int kb = 0; kb < 8; kb++) {
            bhr[kb] = *(const f16x8*)(bph + kb * 16);
            blr[kb] = *(const f16x8*)(bpl + kb * 16);
        }

        // ---- regs -> (hi,lo) fp16 swizzled LDS ----
        #pragma unroll
        for (int p = 0; p < AREG; p++) {
            int row = srow + p * 8;
            float4 v = pa[p];
            _Float16 h0 = (_Float16)v.x, h1 = (_Float16)v.y,
                     h2 = (_Float16)v.z, h3 = (_Float16)v.w;
            f16x4 hv = {h0, h1, h2, h3};
            f16x4 lv = {(_Float16)(v.x - (float)h0), (_Float16)(v.y - (float)h1),
                        (_Float16)(v.z - (float)h2), (_Float16)(v.w - (float)h3)};
            int boff = (k4 * 8) ^ ((row & 7) << 4);
            *(f16x4*)(Alds + row * 256 + boff) = hv;
            *(f16x4*)(Alds + LOOFF + row * 256 + boff) = lv;
        }
        __syncthreads();

        // ---- prefetch source s+1 (A2 = plain layout) while MFMA below ----
        if (s + 1 < NSRC) {
            #pragma unroll
            for (int p = 0; p < AREG; p++) {
                int row = srow + p * 8;
                float4 v = make_float4(0.f, 0.f, 0.f, 0.f);
                if (row0 + row < M)
                    v = *(const float4*)(A2 + (size_t)(row0 + row) * KDIM + k4 * 4);
                pa[p] = v;
            }
        }

        // ---- K-loop: pure LDS reads + register B ----
        const int arow = mt0 * 32 + l31;
        #pragma unroll
        for (int kb = 0; kb < 8; kb++) {
            int boff = ((kb * 2 + kslot) * 16) ^ ((arow & 7) << 4);
            const char* rp = Alds + arow * 256 + boff;
            f16x8 ah = *(const f16x8*)(rp);
            f16x8 al = *(const f16x8*)(rp + LOOFF);
            acc = __builtin_amdgcn_mfma_f32_32x32x16_f16(al, bhr[kb], acc, 0, 0, 0);
            acc = __builtin_amdgcn_mfma_f32_32x32x16_f16(ah, blr[kb], acc, 0, 0, 0);
            acc = __builtin_amdgcn_mfma_f32_32x32x16_f16(ah, bhr[kb], acc, 0, 0, 0);
        }
    }

    float bv = 0.0f;
    if (BIAS) bv = bias[n0 + l31];

    if constexpr (FUSE_MAXK) {
        // ---- h-tile -> LDS (staging LDS dead; BM*512B = exact overlay) ----
        __syncthreads();
        float* ht = (float*)Alds;   // [BM][128]
        #pragma unroll
        for (int r = 0; r < 16; r++) {
            int row = (r & 3) + 8 * (r >> 2) + 4 * kslot;
            ht[row * 128 + n0 + l31] = acc[r] + bv;
        }
        __syncthreads();
        // ---- per-row top-32 + chunked hsc write; wave w: rows w*8.. ----
        float* slab = hsc_out + (size_t)(lane >> 3) * CHSTRIDE;
        #pragma unroll 1
        for (int rr = 0; rr < BM / 4; rr++) {
            int row = w * (BM / 4) + rr;
            float2 v = *(const float2*)(ht + row * 128 + lane * 2);
            float2 o = maxk_row(v, lane);
            int n = row0 + row;
            if (n < M)
                ((float2*)slab)[(size_t)n * 8 + (lane & 7)] = o;
        }
    } else if constexpr (FUSE_OUT) {
        // ---- h-tile -> LDS, 16B-unit XOR swizzle (write: col fixed/lane,
        //      rows vary -> conflict-free; read: rows/lane at same col-range
        //      -> swizzle spreads to ~4-way) ----
        __syncthreads();
        float* ht = (float*)Alds;   // [32][128] swizzled
        const int colg = n0 + l31;
        const int c4w = colg >> 2, cw = colg & 3;
        #pragma unroll
        for (int r = 0; r < 16; r++) {
            int row = (r & 3) + 8 * (r >> 2) + 4 * kslot;
            ht[row * 128 + (((c4w ^ (row & 7)) << 2) + cw)] = acc[r];
        }
        __syncthreads();
        if (w < 2) {
            // out tile: cols ow = w*32 + l31 of 64; A = h rows l31, K=128
            const int ow = w * 32 + l31;
            const _Float16* oph = Oh + (size_t)ow * 128 + kslot * 8;
            const _Float16* opl = Ol + (size_t)ow * 128 + kslot * 8;
            f16x8 obh[8], obl[8];
            #pragma unroll
            for (int kb = 0; kb < 8; kb++) {
                obh[kb] = *(const f16x8*)(oph + kb * 16);
                obl[kb] = *(const f16x8*)(opl + kb * 16);
            }
            f32x16 acc2;
            #pragma unroll
            for (int e = 0; e < 16; e++) acc2[e] = 0.0f;
            const float* hrow = ht + l31 * 128;
            const int hx = l31 & 7;
            #pragma unroll
            for (int kb = 0; kb < 8; kb++) {
                int c4a = kb * 4 + kslot * 2;
                float4 f0 = *(const float4*)(hrow + (((c4a)     ^ hx) << 2));
                float4 f1 = *(const float4*)(hrow + (((c4a + 1) ^ hx) << 2));
                _Float16 h0 = (_Float16)f0.x, h1 = (_Float16)f0.y,
                         h2 = (_Float16)f0.z, h3 = (_Float16)f0.w,
                         h4 = (_Float16)f1.x, h5 = (_Float16)f1.y,
                         h6 = (_Float16)f1.z, h7 = (_Float16)f1.w;
                f16x8 ah = {h0, h1, h2, h3, h4, h5, h6, h7};
                f16x8 al = {(_Float16)(f0.x - (float)h0), (_Float16)(f0.y - (float)h1),
                            (_Float16)(f0.z - (float)h2), (_Float16)(f0.w - (float)h3),
                            (_Float16)(f1.x - (float)h4), (_Float16)(f1.y - (float)h5),
                            (_Float16)(f1.z - (float)h6), (_Float16)(f1.w - (float)h7)};
                acc2 = __builtin_amdgcn_mfma_f32_32x32x16_f16(al, obh[kb], acc2, 0, 0, 0);
                acc2 = __builtin_amdgcn_mfma_f32_32x32x16_f16(ah, obl[kb], acc2, 0, 0, 0);
                acc2 = __builtin_amdgcn_mfma_f32_32x32x16_f16(ah, obh[kb], acc2, 0, 0, 0);
            }
            const float ob = obias[ow];
            #pragma unroll
            for (int r = 0; r < 16; r++) {
                int row = row0 + (r & 3) + 8 * (r >> 2) + 4 * kslot;
                if (row < M) oout[(size_t)row * 64 + ow] = acc2[r] + ob;
            }
        }
    } else {
        #pragma unroll
        for (int r = 0; r < 16; r++) {
            int row = row0 + mt0 * 32 + (r & 3) + 8 * (r >> 2) + 4 * kslot;
            if (row < M) C[(size_t)row * BN + n0 + l31] = acc[r] + bv;
        }
    }
}

// ---------------------------------------------------------------------------
extern "C" void kernel_launch(void* const* d_in, const int* in_sizes, int n_in,
                              void* d_out, int out_size, void* d_ws, size_t ws_size,
                              hipStream_t stream) {
    const float* x       = (const float*)d_in[0];
    const float* W_in    = (const float*)d_in[1];
    const float* b_in    = (const float*)d_in[2];
    const float* W_self  = (const float*)d_in[3];
    const float* W_neigh = (const float*)d_in[4];
    const float* W_out   = (const float*)d_in[5];
    const float* b_out   = (const float*)d_in[6];
    const int*   eidx    = (const int*)d_in[7];

    const int N = NNODE, E = 800000;
    const int* src = eidx;
    const int* dst = eidx + E;

    char* ws = (char*)d_ws;
    float* slabA = (float*)(ws);                // 25.6 MB: layer-1 hsc
    float* slabB = (float*)(ws + 25600000);     // 25.6 MB: layer-2 hsc
    float* agg   = (float*)(ws + 51200000);     // 25.6 MB
    int* cnt     = (int*)(ws + 76800000);       // 200 KB
    int* row_ptr = (int*)(ws + 77000000);       // 200 KB
    int* cursor  = (int*)(ws + 77200016);       // 200 KB
    int* col     = (int*)(ws + 77400016);       // 3.2 MB
    _Float16* wb = (_Float16*)(ws + 80600016);  // 384 KB weight slots
    int* bsum    = (int*)(ws + 81000016);       // 1 KB scan block sums

    const _Float16* WinT_h  = wb + (size_t)0 * 16384;
    const _Float16* WinT_l  = wb + (size_t)1 * 16384;
    const _Float16* WoutT_h = wb + (size_t)10 * 16384;
    const _Float16* WoutT_l = wb + (size_t)11 * 16384;

    const int NB = (N + 255) / 256;                   // 196 scan blocks
    const int EG = ((E + ECHUNK - 1) / ECHUNK) * 8;   // 2000 xcd-chunked blocks
    const int AG = ((N + ANPB - 1) / ANPB) * 8;       // 25000 aggregate blocks
    const int G32 = (N + 31) / 32;                    // 1563 BM=32 gemm blocks

    hipMemsetAsync(cnt, 0, N * sizeof(int), stream);
    hist_kernel<<<EG, 256, 0, stream>>>(src, cnt, E);
    scan1_kernel<<<NB, 256, 0, stream>>>(cnt, row_ptr, bsum, N);
    scan2_kernel<<<1, 256, 0, stream>>>(bsum, NB);
    scan3_kernel<<<NB, 256, 0, stream>>>(bsum, row_ptr, cursor, N, E);
    scatter_kernel<<<EG, 256, 0, stream>>>(src, dst, cursor, col, E);
    sortrows_kernel<<<(N + 3) / 4, 256, 0, stream>>>(row_ptr, col, N);
    conv_wt_kernel<<<(90112 + 255) / 256, 256, 0, stream>>>(W_in, W_self, W_neigh, W_out, wb);

    // layer-1 hs = maxk(x @ W_in + b_in)  [fused] -> slabA (chunked)
    gemm_mfma<128, false, true, false, true, false><<<G32, 256, 0, stream>>>(
        x, nullptr, WinT_h, WinT_l, nullptr, nullptr, b_in, nullptr, slabA,
        nullptr, nullptr, nullptr, nullptr, N);

    // layer 1: agg(slabA); hs2 = maxk(hs@Ws0 + agg@Wn0) [fused] -> slabB
    aggregate_kernel<<<AG, 256, 0, stream>>>(slabA, row_ptr, col, agg, N);
    gemm_mfma<128, true, false, true, true, false><<<G32, 256, 0, stream>>>(
        slabA, agg, wb + (size_t)2 * 16384, wb + (size_t)3 * 16384,
        wb + (size_t)6 * 16384, wb + (size_t)7 * 16384, nullptr, nullptr, slabB,
        nullptr, nullptr, nullptr, nullptr, N);

    // layer 2: agg(slabB); h = hs@Ws1 + agg@Wn1, then FUSED out = h@W_out+b_out
    aggregate_kernel<<<AG, 256, 0, stream>>>(slabB, row_ptr, col, agg, N);
    gemm_mfma<128, true, false, true, false, true><<<G32, 256, 0, stream>>>(
        slabB, agg, wb + (size_t)4 * 16384, wb + (size_t)5 * 16384,
        wb + (size_t)8 * 16384, wb + (size_t)9 * 16384, nullptr, nullptr, nullptr,
        WoutT_h, WoutT_l, b_out, (float*)d_out, N);
}